// Round 1
// baseline (654.640 us; speedup 1.0000x reference)
//
#include <hip/hip_runtime.h>

#define NN 50000
#define NE 1600000
#define INDIM 256
#define HIDIM 128
#define OUTDIM 64

// ---------------- init / degree ----------------

__global__ void k_zero(int* __restrict__ cnt, int* __restrict__ fill, int n) {
    int i = blockIdx.x * 256 + threadIdx.x;
    if (i < n) { cnt[i] = 0; fill[i] = 0; }
}

__global__ void k_hist(const int* __restrict__ col, int* __restrict__ cnt, int e) {
    int i = blockIdx.x * 256 + threadIdx.x;
    if (i < e) atomicAdd(&cnt[col[i]], 1);
}

__global__ void k_dinv(const int* __restrict__ cnt, float* __restrict__ dinv, int n) {
    int i = blockIdx.x * 256 + threadIdx.x;
    if (i < n) dinv[i] = rsqrtf((float)(cnt[i] + 1));   // +1 self loop; deg>=1 always
}

// ---------------- exclusive scan (3 kernels) ----------------

__global__ void k_scan_part(const int* __restrict__ cnt, int* __restrict__ row_ptr,
                            int* __restrict__ blocksum, int n) {
    __shared__ int wsum[16];
    __shared__ int woff[16];
    int tid = threadIdx.x, lane = tid & 63, wid = tid >> 6;
    int i = blockIdx.x * 1024 + tid;
    int v = (i < n) ? cnt[i] : 0;
    int incl = v;
#pragma unroll
    for (int off = 1; off < 64; off <<= 1) {
        int t = __shfl_up(incl, off);
        if (lane >= off) incl += t;
    }
    if (lane == 63) wsum[wid] = incl;
    __syncthreads();
    if (wid == 0 && lane < 16) {
        int wv = wsum[lane];
        int wincl = wv;
#pragma unroll
        for (int off = 1; off < 16; off <<= 1) {
            int t = __shfl_up(wincl, off);
            if (lane >= off) wincl += t;
        }
        woff[lane] = wincl - wv;
    }
    __syncthreads();
    int excl = incl - v + woff[wid];
    if (i < n) row_ptr[i] = excl;
    if (tid == 1023) blocksum[blockIdx.x] = excl + v;
}

__global__ void k_scan_sums(const int* __restrict__ blocksum, int* __restrict__ blockoff,
                            int* __restrict__ row_ptr, int nchunks, int n) {
    int lane = threadIdx.x;
    int v = (lane < nchunks) ? blocksum[lane] : 0;
    int incl = v;
#pragma unroll
    for (int off = 1; off < 64; off <<= 1) {
        int t = __shfl_up(incl, off);
        if (lane >= off) incl += t;
    }
    blockoff[lane] = incl - v;
    if (lane == nchunks - 1) row_ptr[n] = incl;  // total = E
}

__global__ void k_scan_add(int* __restrict__ row_ptr, const int* __restrict__ blockoff, int n) {
    int i = blockIdx.x * 1024 + threadIdx.x;
    if (i < n) row_ptr[i] += blockoff[blockIdx.x];
}

// ---------------- CSR placement ----------------

__global__ void k_place(const int* __restrict__ row, const int* __restrict__ col,
                        const float* __restrict__ dinv, const int* __restrict__ row_ptr,
                        int* __restrict__ fill, int* __restrict__ ssrc,
                        float* __restrict__ snorm, int e) {
    int i = blockIdx.x * 256 + threadIdx.x;
    if (i >= e) return;
    int s = row[i], d = col[i];
    int pos = row_ptr[d] + atomicAdd(&fill[d], 1);
    ssrc[pos]  = s;
    snorm[pos] = dinv[s] * dinv[d];
}

// ---------------- f32 GEMM: A[n x K] @ W[K x M] -> out[n x M] ----------------
// 64-row tile, full-M width, 256 threads, float4 micro-tiles.

template <int K, int M>
__global__ void k_gemm(const float* __restrict__ A, const float* __restrict__ W,
                       float* __restrict__ out, int n) {
    constexpr int KC  = 16;
    constexpr int NTX = M / 4;       // threads across columns
    constexpr int NTY = 256 / NTX;   // row groups
    constexpr int RT  = 64 / NTY;    // rows per thread
    __shared__ float xs[64][KC];
    __shared__ float ws[KC][M];
    int tid = threadIdx.x;
    int tx = tid % NTX, ty = tid / NTX;
    int row0 = blockIdx.x * 64;

    float4 acc[RT];
#pragma unroll
    for (int i = 0; i < RT; i++) acc[i] = make_float4(0.f, 0.f, 0.f, 0.f);

    for (int k0 = 0; k0 < K; k0 += KC) {
        {   // stage x tile: 64 rows x 16 k -> one float4/thread
            int r  = tid >> 2;
            int kq = (tid & 3) << 2;
            int gr = row0 + r;
            float4 xv = make_float4(0.f, 0.f, 0.f, 0.f);
            if (gr < n) xv = *(const float4*)(A + (size_t)gr * K + k0 + kq);
            *(float4*)&xs[r][kq] = xv;
        }
        // stage W tile: KC x M
        for (int idx = tid * 4; idx < KC * M; idx += 1024) {
            int kk = idx / M, j = idx % M;
            *(float4*)&ws[kk][j] = *(const float4*)(W + (size_t)(k0 + kk) * M + j);
        }
        __syncthreads();
#pragma unroll
        for (int kk = 0; kk < KC; kk++) {
            float4 wv = *(float4*)&ws[kk][tx * 4];
#pragma unroll
            for (int i = 0; i < RT; i++) {
                float a = xs[ty + NTY * i][kk];
                acc[i].x += a * wv.x;
                acc[i].y += a * wv.y;
                acc[i].z += a * wv.z;
                acc[i].w += a * wv.w;
            }
        }
        __syncthreads();
    }
#pragma unroll
    for (int i = 0; i < RT; i++) {
        int gr = row0 + ty + NTY * i;
        if (gr < n) *(float4*)(out + (size_t)gr * M + tx * 4) = acc[i];
    }
}

// ---------------- pull aggregation ----------------
// layer 1: HIDIM=128, float2/lane, fused bias+ReLU
__global__ void k_agg1(const float* __restrict__ h, const float* __restrict__ dinv,
                       const int* __restrict__ row_ptr, const int* __restrict__ ssrc,
                       const float* __restrict__ snorm, const float* __restrict__ b1,
                       float* __restrict__ hr) {
    int wid = threadIdx.x >> 6, lane = threadIdx.x & 63;
    int d = blockIdx.x * 4 + wid;           // 12500 * 4 == 50000 exactly
    float dv = dinv[d];
    int f = lane * 2;
    const float* hd = h + (size_t)d * HIDIM + f;
    float ax = hd[0] * dv * dv;
    float ay = hd[1] * dv * dv;
    int e0 = row_ptr[d], e1 = row_ptr[d + 1];
    for (int e = e0; e < e1; e++) {
        int s = ssrc[e];
        float nm = snorm[e];
        const float* hs = h + (size_t)s * HIDIM + f;
        ax += hs[0] * nm;
        ay += hs[1] * nm;
    }
    ax = fmaxf(ax + b1[f], 0.f);
    ay = fmaxf(ay + b1[f + 1], 0.f);
    float* o = hr + (size_t)d * HIDIM + f;
    o[0] = ax;
    o[1] = ay;
}

// layer 2: OUTDIM=64, 1 float/lane, bias only
__global__ void k_agg2(const float* __restrict__ h2, const float* __restrict__ dinv,
                       const int* __restrict__ row_ptr, const int* __restrict__ ssrc,
                       const float* __restrict__ snorm, const float* __restrict__ b2,
                       float* __restrict__ out) {
    int wid = threadIdx.x >> 6, lane = threadIdx.x & 63;
    int d = blockIdx.x * 4 + wid;
    float dv = dinv[d];
    float acc = h2[(size_t)d * OUTDIM + lane] * dv * dv;
    int e0 = row_ptr[d], e1 = row_ptr[d + 1];
    for (int e = e0; e < e1; e++) {
        int s = ssrc[e];
        float nm = snorm[e];
        acc += h2[(size_t)s * OUTDIM + lane] * nm;
    }
    out[(size_t)d * OUTDIM + lane] = acc + b2[lane];
}

// ---------------- launch ----------------

extern "C" void kernel_launch(void* const* d_in, const int* in_sizes, int n_in,
                              void* d_out, int out_size, void* d_ws, size_t ws_size,
                              hipStream_t stream) {
    const float* x   = (const float*)d_in[0];
    const int*   ei  = (const int*)d_in[1];
    const float* W1  = (const float*)d_in[2];
    const float* b1  = (const float*)d_in[3];
    const float* W2  = (const float*)d_in[4];
    const float* b2  = (const float*)d_in[5];
    float* out = (float*)d_out;

    const int* row = ei;        // sources
    const int* col = ei + NE;   // destinations

    size_t off = 0;
    auto alloc = [&](size_t bytes) {
        void* p = (char*)d_ws + off;
        off += (bytes + 255) & ~(size_t)255;
        return p;
    };
    float* dinv     = (float*)alloc((size_t)NN * 4);
    int*   cnt      = (int*)  alloc((size_t)NN * 4);
    int*   fill     = (int*)  alloc((size_t)NN * 4);
    int*   row_ptr  = (int*)  alloc((size_t)(NN + 1) * 4);
    int*   blocksum = (int*)  alloc(64 * 4);
    int*   blockoff = (int*)  alloc(64 * 4);
    int*   ssrc     = (int*)  alloc((size_t)NE * 4);
    float* snorm    = (float*)alloc((size_t)NE * 4);
    float* h1       = (float*)alloc((size_t)NN * HIDIM * 4);
    float* hr       = (float*)alloc((size_t)NN * HIDIM * 4);
    float* h2       = (float*)alloc((size_t)NN * OUTDIM * 4);

    const int nchunks = (NN + 1023) / 1024;  // 49

    k_zero<<<(NN + 255) / 256, 256, 0, stream>>>(cnt, fill, NN);
    k_hist<<<(NE + 255) / 256, 256, 0, stream>>>(col, cnt, NE);
    k_dinv<<<(NN + 255) / 256, 256, 0, stream>>>(cnt, dinv, NN);

    k_scan_part<<<nchunks, 1024, 0, stream>>>(cnt, row_ptr, blocksum, NN);
    k_scan_sums<<<1, 64, 0, stream>>>(blocksum, blockoff, row_ptr, nchunks, NN);
    k_scan_add<<<nchunks, 1024, 0, stream>>>(row_ptr, blockoff, NN);

    k_place<<<(NE + 255) / 256, 256, 0, stream>>>(row, col, dinv, row_ptr, fill,
                                                  ssrc, snorm, NE);

    k_gemm<INDIM, HIDIM><<<(NN + 63) / 64, 256, 0, stream>>>(x, W1, h1, NN);
    k_agg1<<<NN / 4, 256, 0, stream>>>(h1, dinv, row_ptr, ssrc, snorm, b1, hr);
    k_gemm<HIDIM, OUTDIM><<<(NN + 63) / 64, 256, 0, stream>>>(hr, W2, h2, NN);
    k_agg2<<<NN / 4, 256, 0, stream>>>(h2, dinv, row_ptr, ssrc, snorm, b2, out);
}

// Round 2
// 490.790 us; speedup vs baseline: 1.3338x; 1.3338x over previous
//
#include <hip/hip_runtime.h>

#define NN 50000
#define NE 1600000
#define INDIM 256
#define HIDIM 128
#define OUTDIM 64

typedef unsigned int uint;
typedef unsigned short ushort;

__device__ __forceinline__ ushort f2bf(float f) {
    uint u = __float_as_uint(f);
    uint r = (u + 0x7FFFu + ((u >> 16) & 1u)) >> 16;   // RTNE
    return (ushort)r;
}
__device__ __forceinline__ float bf_lo(uint u) { return __uint_as_float(u << 16); }
__device__ __forceinline__ float bf_hi(uint u) { return __uint_as_float(u & 0xFFFF0000u); }
__device__ __forceinline__ float bf1(ushort u) { return __uint_as_float(((uint)u) << 16); }

// ---------------- init / degree ----------------

__global__ void k_zero(int* __restrict__ cnt, int* __restrict__ fill, int n) {
    int i = blockIdx.x * 256 + threadIdx.x;
    if (i < n) { cnt[i] = 0; fill[i] = 0; }
}

__global__ void k_hist(const int* __restrict__ col, int* __restrict__ cnt, int e) {
    int i = blockIdx.x * 256 + threadIdx.x;
    if (i < e) atomicAdd(&cnt[col[i]], 1);
}

__global__ void k_dinv(const int* __restrict__ cnt, float* __restrict__ dinv, int n) {
    int i = blockIdx.x * 256 + threadIdx.x;
    if (i < n) dinv[i] = rsqrtf((float)(cnt[i] + 1));   // +1 self loop
}

// ---------------- exclusive scan (3 kernels) ----------------

__global__ void k_scan_part(const int* __restrict__ cnt, int* __restrict__ row_ptr,
                            int* __restrict__ blocksum, int n) {
    __shared__ int wsum[16];
    __shared__ int woff[16];
    int tid = threadIdx.x, lane = tid & 63, wid = tid >> 6;
    int i = blockIdx.x * 1024 + tid;
    int v = (i < n) ? cnt[i] : 0;
    int incl = v;
#pragma unroll
    for (int off = 1; off < 64; off <<= 1) {
        int t = __shfl_up(incl, off);
        if (lane >= off) incl += t;
    }
    if (lane == 63) wsum[wid] = incl;
    __syncthreads();
    if (wid == 0 && lane < 16) {
        int wv = wsum[lane];
        int wincl = wv;
#pragma unroll
        for (int off = 1; off < 16; off <<= 1) {
            int t = __shfl_up(wincl, off);
            if (lane >= off) wincl += t;
        }
        woff[lane] = wincl - wv;
    }
    __syncthreads();
    int excl = incl - v + woff[wid];
    if (i < n) row_ptr[i] = excl;
    if (tid == 1023) blocksum[blockIdx.x] = excl + v;
}

__global__ void k_scan_sums(const int* __restrict__ blocksum, int* __restrict__ blockoff,
                            int* __restrict__ row_ptr, int nchunks, int n) {
    int lane = threadIdx.x;
    int v = (lane < nchunks) ? blocksum[lane] : 0;
    int incl = v;
#pragma unroll
    for (int off = 1; off < 64; off <<= 1) {
        int t = __shfl_up(incl, off);
        if (lane >= off) incl += t;
    }
    blockoff[lane] = incl - v;
    if (lane == nchunks - 1) row_ptr[n] = incl;
}

__global__ void k_scan_add(int* __restrict__ row_ptr, const int* __restrict__ blockoff, int n) {
    int i = blockIdx.x * 1024 + threadIdx.x;
    if (i < n) row_ptr[i] += blockoff[blockIdx.x];
}

// ---------------- CSR placement ----------------

__global__ void k_place(const int* __restrict__ row, const int* __restrict__ col,
                        const float* __restrict__ dinv, const int* __restrict__ row_ptr,
                        int* __restrict__ fill, int* __restrict__ ssrc,
                        float* __restrict__ snorm, int e) {
    int i = blockIdx.x * 256 + threadIdx.x;
    if (i >= e) return;
    int s = row[i], d = col[i];
    int pos = row_ptr[d] + atomicAdd(&fill[d], 1);
    ssrc[pos]  = s;
    snorm[pos] = dinv[s] * dinv[d];
}

// ---------------- f32 GEMM: A[n x K](f32) @ W[K x M](f32) -> out[n x M](bf16) ----

template <int K, int M>
__global__ void k_gemm(const float* __restrict__ A, const float* __restrict__ W,
                       ushort* __restrict__ out, int n) {
    constexpr int KC  = 16;
    constexpr int NTX = M / 4;       // threads across columns
    constexpr int NTY = 256 / NTX;   // row groups
    constexpr int RT  = 64 / NTY;    // rows per thread
    __shared__ float xs[64][KC];
    __shared__ float ws[KC][M];
    int tid = threadIdx.x;
    int tx = tid % NTX, ty = tid / NTX;
    int row0 = blockIdx.x * 64;

    float4 acc[RT];
#pragma unroll
    for (int i = 0; i < RT; i++) acc[i] = make_float4(0.f, 0.f, 0.f, 0.f);

    for (int k0 = 0; k0 < K; k0 += KC) {
        {
            int r  = tid >> 2;
            int kq = (tid & 3) << 2;
            int gr = row0 + r;
            float4 xv = make_float4(0.f, 0.f, 0.f, 0.f);
            if (gr < n) xv = *(const float4*)(A + (size_t)gr * K + k0 + kq);
            *(float4*)&xs[r][kq] = xv;
        }
        for (int idx = tid * 4; idx < KC * M; idx += 1024) {
            int kk = idx / M, j = idx % M;
            *(float4*)&ws[kk][j] = *(const float4*)(W + (size_t)(k0 + kk) * M + j);
        }
        __syncthreads();
#pragma unroll
        for (int kk = 0; kk < KC; kk++) {
            float4 wv = *(float4*)&ws[kk][tx * 4];
#pragma unroll
            for (int i = 0; i < RT; i++) {
                float a = xs[ty + NTY * i][kk];
                acc[i].x += a * wv.x;
                acc[i].y += a * wv.y;
                acc[i].z += a * wv.z;
                acc[i].w += a * wv.w;
            }
        }
        __syncthreads();
    }
#pragma unroll
    for (int i = 0; i < RT; i++) {
        int gr = row0 + ty + NTY * i;
        if (gr < n) {
            ushort4 o;
            o.x = f2bf(acc[i].x);
            o.y = f2bf(acc[i].y);
            o.z = f2bf(acc[i].z);
            o.w = f2bf(acc[i].w);
            *(ushort4*)(out + (size_t)gr * M + tx * 4) = o;
        }
    }
}

// ---------------- pull aggregation ----------------
// layer 1: h1b bf16 [NN][128]; lane handles features {2*lane, 2*lane+1} via one uint
__global__ void k_agg1(const ushort* __restrict__ h1b, const float* __restrict__ dinv,
                       const int* __restrict__ row_ptr, const int* __restrict__ ssrc,
                       const float* __restrict__ snorm, const float* __restrict__ b1,
                       float* __restrict__ hr) {
    int wid = threadIdx.x >> 6, lane = threadIdx.x & 63;
    int d = blockIdx.x * 4 + wid;           // 12500 * 4 == 50000
    float dv = dinv[d];
    float dv2 = dv * dv;
    int f = lane * 2;
    uint ud = *(const uint*)(h1b + (size_t)d * HIDIM + f);
    float ax = bf_lo(ud) * dv2;
    float ay = bf_hi(ud) * dv2;
    int e0 = row_ptr[d], e1 = row_ptr[d + 1];
    int e = e0;
    for (; e + 1 < e1; e += 2) {
        int s0 = ssrc[e], s1 = ssrc[e + 1];
        float n0 = snorm[e], n1 = snorm[e + 1];
        uint u0 = *(const uint*)(h1b + (size_t)s0 * HIDIM + f);
        uint u1 = *(const uint*)(h1b + (size_t)s1 * HIDIM + f);
        ax += bf_lo(u0) * n0;
        ay += bf_hi(u0) * n0;
        ax += bf_lo(u1) * n1;
        ay += bf_hi(u1) * n1;
    }
    if (e < e1) {
        int s0 = ssrc[e];
        float n0 = snorm[e];
        uint u0 = *(const uint*)(h1b + (size_t)s0 * HIDIM + f);
        ax += bf_lo(u0) * n0;
        ay += bf_hi(u0) * n0;
    }
    ax = fmaxf(ax + b1[f], 0.f);
    ay = fmaxf(ay + b1[f + 1], 0.f);
    float* o = hr + (size_t)d * HIDIM + f;
    o[0] = ax;
    o[1] = ay;
}

// layer 2: h2b bf16 [NN][64]; lane handles 1 feature
__global__ void k_agg2(const ushort* __restrict__ h2b, const float* __restrict__ dinv,
                       const int* __restrict__ row_ptr, const int* __restrict__ ssrc,
                       const float* __restrict__ snorm, const float* __restrict__ b2,
                       float* __restrict__ out) {
    int wid = threadIdx.x >> 6, lane = threadIdx.x & 63;
    int d = blockIdx.x * 4 + wid;
    float dv = dinv[d];
    float acc = bf1(h2b[(size_t)d * OUTDIM + lane]) * dv * dv;
    int e0 = row_ptr[d], e1 = row_ptr[d + 1];
    int e = e0;
    for (; e + 1 < e1; e += 2) {
        int s0 = ssrc[e], s1 = ssrc[e + 1];
        float n0 = snorm[e], n1 = snorm[e + 1];
        float v0 = bf1(h2b[(size_t)s0 * OUTDIM + lane]);
        float v1 = bf1(h2b[(size_t)s1 * OUTDIM + lane]);
        acc += v0 * n0;
        acc += v1 * n1;
    }
    if (e < e1) {
        int s0 = ssrc[e];
        float n0 = snorm[e];
        acc += bf1(h2b[(size_t)s0 * OUTDIM + lane]) * n0;
    }
    out[(size_t)d * OUTDIM + lane] = acc + b2[lane];
}

// ---------------- launch ----------------

extern "C" void kernel_launch(void* const* d_in, const int* in_sizes, int n_in,
                              void* d_out, int out_size, void* d_ws, size_t ws_size,
                              hipStream_t stream) {
    const float* x   = (const float*)d_in[0];
    const int*   ei  = (const int*)d_in[1];
    const float* W1  = (const float*)d_in[2];
    const float* b1  = (const float*)d_in[3];
    const float* W2  = (const float*)d_in[4];
    const float* b2  = (const float*)d_in[5];
    float* out = (float*)d_out;

    const int* row = ei;        // sources
    const int* col = ei + NE;   // destinations

    size_t off = 0;
    auto alloc = [&](size_t bytes) {
        void* p = (char*)d_ws + off;
        off += (bytes + 255) & ~(size_t)255;
        return p;
    };
    float*  dinv     = (float*)alloc((size_t)NN * 4);
    int*    cnt      = (int*)  alloc((size_t)NN * 4);
    int*    fill     = (int*)  alloc((size_t)NN * 4);
    int*    row_ptr  = (int*)  alloc((size_t)(NN + 1) * 4);
    int*    blocksum = (int*)  alloc(64 * 4);
    int*    blockoff = (int*)  alloc(64 * 4);
    int*    ssrc     = (int*)  alloc((size_t)NE * 4);
    float*  snorm    = (float*)alloc((size_t)NE * 4);
    ushort* h1b      = (ushort*)alloc((size_t)NN * HIDIM * 2);
    float*  hr       = (float*) alloc((size_t)NN * HIDIM * 4);
    ushort* h2b      = (ushort*)alloc((size_t)NN * OUTDIM * 2);

    const int nchunks = (NN + 1023) / 1024;  // 49

    k_zero<<<(NN + 255) / 256, 256, 0, stream>>>(cnt, fill, NN);
    k_hist<<<(NE + 255) / 256, 256, 0, stream>>>(col, cnt, NE);
    k_dinv<<<(NN + 255) / 256, 256, 0, stream>>>(cnt, dinv, NN);

    k_scan_part<<<nchunks, 1024, 0, stream>>>(cnt, row_ptr, blocksum, NN);
    k_scan_sums<<<1, 64, 0, stream>>>(blocksum, blockoff, row_ptr, nchunks, NN);
    k_scan_add<<<nchunks, 1024, 0, stream>>>(row_ptr, blockoff, NN);

    k_place<<<(NE + 255) / 256, 256, 0, stream>>>(row, col, dinv, row_ptr, fill,
                                                  ssrc, snorm, NE);

    k_gemm<INDIM, HIDIM><<<(NN + 63) / 64, 256, 0, stream>>>(x, W1, h1b, NN);
    k_agg1<<<NN / 4, 256, 0, stream>>>(h1b, dinv, row_ptr, ssrc, snorm, b1, hr);
    k_gemm<HIDIM, OUTDIM><<<(NN + 63) / 64, 256, 0, stream>>>(hr, W2, h2b, NN);
    k_agg2<<<NN / 4, 256, 0, stream>>>(h2b, dinv, row_ptr, ssrc, snorm, b2, out);
}